// Round 5
// baseline (199.991 us; speedup 1.0000x reference)
//
#include <hip/hip_runtime.h>

// DiffKS: x = invert_lpc(y, A_exc)  [order-6 time-varying FIR]
//         out = sample_wise_lpc(x, A_loop)  [order-2 time-varying IIR]
// B=48, T=88200, fp32.
//
// R5: pipelined multi-step waves with exact IIR state chaining.
//  - Wave owns 992 consecutive outputs = 4 steps x 256 samples (4/lane).
//  - Step 0 has a 32-sample zero-state warm-up (lanes 0..7); steps 1..3
//    chain the EXACT state from the previous step (lane 63 broadcast),
//    injected into the scan as y_in = c_excl + P_excl * s_chain.
//    (P_excl exact for lanes < 8; for lanes >= 8 both true and truncated
//    P have norm <= 1.5e-5 -> error ~1e-5.)
//  - Software prefetch: step k+1's per-lane 9x float4 (y, A_exc x6,
//    A_loop x2) issued before computing step k -> load latency exposed
//    once per wave, not once per chunk.
//  - Scan: d=1,2,4 full affine + d=8 c-only (truncation err < 1e-9).

#define T_LEN 88200
#define B_N   48
#define WUP   32
#define STEP  256          // samples per step (4 per lane)
#define NSTEP 4
#define OUT_W 992          // NSTEP*STEP - WUP... wave output span
#define NCHW  89           // ceil(T_LEN / OUT_W)
#define WPB   4

struct StepData { float4 yv, ae[6], al[2]; };

__device__ __forceinline__ float4 zero4() { return make_float4(0.f, 0.f, 0.f, 0.f); }

__device__ __forceinline__ float4 ld_g(const float* __restrict__ p, int t) {
    if (t >= 0 && t + 3 < T_LEN) return *(const float4*)(p + t);
    return zero4();
}

__device__ __forceinline__ StepData load_step(const float* __restrict__ yb,
                                              const float* __restrict__ aeb,
                                              const float* __restrict__ alb,
                                              int t) {
    StepData r;
    if (t >= 0 && t + 3 < T_LEN) {
        r.yv = *(const float4*)(yb + t);
        const float4* pa = (const float4*)(aeb + (size_t)t * 6);
#pragma unroll
        for (int i = 0; i < 6; ++i) r.ae[i] = pa[i];
        const float4* pl = (const float4*)(alb + (size_t)t * 2);
        r.al[0] = pl[0]; r.al[1] = pl[1];
    } else {
        r.yv = zero4();
#pragma unroll
        for (int i = 0; i < 6; ++i) r.ae[i] = zero4();
        r.al[0] = r.al[1] = zero4();
    }
    return r;
}

__global__ __launch_bounds__(256, 4) void diffks_kernel(
    const float* __restrict__ y, const float* __restrict__ A_exc,
    const float* __restrict__ A_loop, float* __restrict__ out) {
    const int tid  = threadIdx.x;
    const int widx = tid >> 6;
    const int lane = tid & 63;
    const int w = blockIdx.x * WPB + widx;      // 0..4271 (grid exact)
    const int b = w / NCHW;
    const int c = w - b * NCHW;
    const int s = c * OUT_W;

    const float* yb  = y      + (size_t)b * T_LEN;
    const float* aeb = A_exc  + (size_t)b * T_LEN * 6;
    const float* alb = A_loop + (size_t)b * T_LEN * 2;
    float*       ob  = out    + (size_t)b * T_LEN;

    int t = s - WUP + 4 * lane;                 // lane's step-0 start (mult 4)
    StepData cur = load_step(yb, aeb, alb, t);
    float sc0 = 0.f, sc1 = 0.f;                 // chained state [y1, y2]

#pragma unroll
    for (int k = 0; k < NSTEP; ++k) {
        StepData nxt;
        if (k < NSTEP - 1) nxt = load_step(yb, aeb, alb, t + STEP);

        // y history (guarded; mostly L1-hot from neighbor lanes)
        const float4 hm2 = ld_g(yb, t - 8);
        const float4 hm1 = ld_g(yb, t - 4);
        const float yw[12] = { hm2.x, hm2.y, hm2.z, hm2.w,
                               hm1.x, hm1.y, hm1.z, hm1.w,
                               cur.yv.x, cur.yv.y, cur.yv.z, cur.yv.w };
        const float* aef = (const float*)cur.ae;   // 24 floats
        const float* alf = (const float*)cur.al;   // 8 floats

        // ---- FIR + local affine compose over 4 samples ----
        float xs[4], a1s[4], a2s[4];
        float p00 = 1.f, p01 = 0.f, p10 = 0.f, p11 = 1.f, c0 = 0.f, c1 = 0.f;
#pragma unroll
        for (int j = 0; j < 4; ++j) {
            float xv = yw[8 + j];
#pragma unroll
            for (int kk = 1; kk <= 6; ++kk)
                xv = fmaf(aef[j * 6 + (kk - 1)], yw[8 + j - kk], xv);
            xs[j] = xv;
            const float a1 = alf[2 * j], a2 = alf[2 * j + 1];
            a1s[j] = a1; a2s[j] = a2;
            const float n00 = fmaf(-a1, p00, -a2 * p10);
            const float n01 = fmaf(-a1, p01, -a2 * p11);
            p10 = p00; p11 = p01; p00 = n00; p01 = n01;
            const float nc0 = fmaf(-a1, c0, fmaf(-a2, c1, xv));
            c1 = c0; c0 = nc0;
        }

        // ---- wave scan: d=1,2,4 full; d=8 c-only ----
#pragma unroll
        for (int d = 1; d <= 4; d <<= 1) {
            const float q00 = __shfl_up(p00, d, 64), q01 = __shfl_up(p01, d, 64);
            const float q10 = __shfl_up(p10, d, 64), q11 = __shfl_up(p11, d, 64);
            const float qc0 = __shfl_up(c0, d, 64),  qc1 = __shfl_up(c1, d, 64);
            if (lane >= d) {
                const float m00 = fmaf(p00, q00, p01 * q10);
                const float m01 = fmaf(p00, q01, p01 * q11);
                const float m10 = fmaf(p10, q00, p11 * q10);
                const float m11 = fmaf(p10, q01, p11 * q11);
                const float nc0 = fmaf(p00, qc0, fmaf(p01, qc1, c0));
                const float nc1 = fmaf(p10, qc0, fmaf(p11, qc1, c1));
                p00 = m00; p01 = m01; p10 = m10; p11 = m11; c0 = nc0; c1 = nc1;
            }
        }
        {
            const float qc0 = __shfl_up(c0, 8, 64), qc1 = __shfl_up(c1, 8, 64);
            if (lane >= 8) {
                const float nc0 = fmaf(p00, qc0, fmaf(p01, qc1, c0));
                const float nc1 = fmaf(p10, qc0, fmaf(p11, qc1, c1));
                c0 = nc0; c1 = nc1;
            }
        }

        // ---- exclusive prefix (P and c), inject chained state ----
        float e00 = __shfl_up(p00, 1, 64), e01 = __shfl_up(p01, 1, 64);
        float e10 = __shfl_up(p10, 1, 64), e11 = __shfl_up(p11, 1, 64);
        float ec0 = __shfl_up(c0, 1, 64),  ec1 = __shfl_up(c1, 1, 64);
        if (lane == 0) { e00 = 1.f; e01 = 0.f; e10 = 0.f; e11 = 1.f;
                         ec0 = 0.f; ec1 = 0.f; }
        float y1 = fmaf(e00, sc0, fmaf(e01, sc1, ec0));
        float y2 = fmaf(e10, sc0, fmaf(e11, sc1, ec1));

        // ---- replay 4 samples ----
        float ov[4];
#pragma unroll
        for (int j = 0; j < 4; ++j) {
            const float yt = fmaf(-a1s[j], y1, fmaf(-a2s[j], y2, xs[j]));
            y2 = y1; y1 = yt;
            ov[j] = yt;
        }

        // ---- chain state out of this step (lane 63's final y1,y2) ----
        sc0 = __shfl(y1, 63, 64);
        sc1 = __shfl(y2, 63, 64);

        // ---- store (skip warm-up region of step 0; guard tail) ----
        if ((k > 0 || lane >= WUP / 4) && t < T_LEN)
            *(float4*)(ob + t) = make_float4(ov[0], ov[1], ov[2], ov[3]);

        t += STEP;
        cur = nxt;
    }
}

extern "C" void kernel_launch(void* const* d_in, const int* in_sizes, int n_in,
                              void* d_out, int out_size, void* d_ws, size_t ws_size,
                              hipStream_t stream) {
    const float* y      = (const float*)d_in[0];
    const float* A_exc  = (const float*)d_in[1];
    const float* A_loop = (const float*)d_in[2];
    float* out = (float*)d_out;

    const int waves = B_N * NCHW;          // 48 * 89 = 4272
    const int grid  = waves / WPB;         // 1068 blocks of 4 waves
    diffks_kernel<<<grid, 256, 0, stream>>>(y, A_exc, A_loop, out);
}

// Round 6
// 191.273 us; speedup vs baseline: 1.0456x; 1.0456x over previous
//
#include <hip/hip_runtime.h>

// DiffKS split-pipeline (R6):
//   Kernel A (FIR): x[t] = y[t] + sum_k A_exc[t,k-1]*y[t-k]  -- pure
//     streaming, embarrassingly parallel, 4 samples/lane, halos via
//     __shfl_up (lanes 0/1 guarded loads). Writes x to workspace.
//   Kernel B (IIR): R3-proven truncated-scan structure on x + A_loop.
//     Window 256 = 32 warm-up + 224 out per wave; scan d=1,2,4 full
//     + d=8 c-only (||P(32)|| <= 1.5e-5 -> truncation ~1e-9).
// Decisive experiment: does a copy-µbench-shaped kernel (A) beat the
// ~3 MB/us wall all fused variants hit?

#define T_LEN 88200
#define B_N   48

// Kernel A geometry
#define WPR   345          // waves per row: ceil(22050 lane-tasks / 64)
// Kernel B geometry
#define OUT_W 224
#define WUP   32
#define NCH   394          // ceil(T_LEN / OUT_W)
#define WPB   4

__device__ __forceinline__ float4 zero4() { return make_float4(0.f, 0.f, 0.f, 0.f); }

__device__ __forceinline__ float4 ld_g(const float* __restrict__ p, int t) {
    // whole-float4 guard; callers guarantee t % 4 == 0
    if (t >= 0 && t + 3 < T_LEN) return *(const float4*)(p + t);
    return zero4();
}

// ---------------- Kernel A: time-varying FIR (invert_lpc) ----------------
__global__ __launch_bounds__(256) void fir_kernel(
    const float* __restrict__ y, const float* __restrict__ A_exc,
    float* __restrict__ x) {
    const int tid  = threadIdx.x;
    const int widx = tid >> 6;
    const int lane = tid & 63;
    const int w = blockIdx.x * 4 + widx;        // 0..16559 (grid exact)
    const int b = w / WPR;
    const int r = w - b * WPR;                  // wave-in-row
    const int t0 = (r * 64 + lane) * 4;         // sample start within row

    const float* yb  = y     + (size_t)b * T_LEN;
    const float* aeb = A_exc + (size_t)b * T_LEN * 6;
    float*       xb  = x     + (size_t)b * T_LEN;

    const bool valid = (t0 + 3 < T_LEN);        // whole-float4 (T_LEN%4==0)
    float4 yv, ae[6];
    if (valid) {
        yv = *(const float4*)(yb + t0);
        const float4* pa = (const float4*)(aeb + (size_t)t0 * 6);
#pragma unroll
        for (int i = 0; i < 6; ++i) ae[i] = pa[i];
    } else {
        yv = zero4();
#pragma unroll
        for (int i = 0; i < 6; ++i) ae[i] = zero4();
    }

    // y history via intra-wave shuffles; lanes 0/1 load halo (zero-padded)
    float4 hm1, hm2;
    hm1.x = __shfl_up(yv.x, 1, 64); hm1.y = __shfl_up(yv.y, 1, 64);
    hm1.z = __shfl_up(yv.z, 1, 64); hm1.w = __shfl_up(yv.w, 1, 64);
    hm2.x = __shfl_up(yv.x, 2, 64); hm2.y = __shfl_up(yv.y, 2, 64);
    hm2.z = __shfl_up(yv.z, 2, 64); hm2.w = __shfl_up(yv.w, 2, 64);
    if (lane == 0) hm1 = ld_g(yb, t0 - 4);
    if (lane <= 1) hm2 = ld_g(yb, t0 - 8);

    const float yw[12] = { hm2.x, hm2.y, hm2.z, hm2.w,
                           hm1.x, hm1.y, hm1.z, hm1.w,
                           yv.x,  yv.y,  yv.z,  yv.w };
    const float* aef = (const float*)ae;        // 24 contiguous floats

    float xv[4];
#pragma unroll
    for (int j = 0; j < 4; ++j) {
        float acc = yw[8 + j];
#pragma unroll
        for (int k = 1; k <= 6; ++k)
            acc = fmaf(aef[j * 6 + (k - 1)], yw[8 + j - k], acc);
        xv[j] = acc;
    }
    if (valid)
        *(float4*)(xb + t0) = make_float4(xv[0], xv[1], xv[2], xv[3]);
}

// ---------------- Kernel B: time-varying IIR via truncated wave scan ----
__global__ __launch_bounds__(256) void iir_kernel(
    const float* __restrict__ x, const float* __restrict__ A_loop,
    float* __restrict__ out) {
    const int tid  = threadIdx.x;
    const int widx = tid >> 6;
    const int lane = tid & 63;
    const int w = blockIdx.x * WPB + widx;      // 0..18911 (grid exact)
    const int b = w / NCH;
    const int c = w - b * NCH;
    const int s  = c * OUT_W;
    const int t0 = s - WUP + 4 * lane;

    const float* xb  = x      + (size_t)b * T_LEN;
    const float* alb = A_loop + (size_t)b * T_LEN * 2;
    float*       ob  = out    + (size_t)b * T_LEN;

    // fully coalesced x load; A_loop 32B/lane stride (line-perfect)
    float4 xv4, al0, al1;
    if (t0 >= 0 && t0 + 3 < T_LEN) {
        xv4 = *(const float4*)(xb + t0);
        const float4* pl = (const float4*)(alb + (size_t)t0 * 2);
        al0 = pl[0]; al1 = pl[1];
    } else {
        xv4 = al0 = al1 = zero4();
    }
    const float xs[4]  = { xv4.x, xv4.y, xv4.z, xv4.w };
    const float alf[8] = { al0.x, al0.y, al0.z, al0.w,
                           al1.x, al1.y, al1.z, al1.w };

    // ---- local affine compose over 4 samples ----
    float a1s[4], a2s[4];
    float p00 = 1.f, p01 = 0.f, p10 = 0.f, p11 = 1.f, c0 = 0.f, c1 = 0.f;
#pragma unroll
    for (int j = 0; j < 4; ++j) {
        const float a1 = alf[2 * j], a2 = alf[2 * j + 1];
        a1s[j] = a1; a2s[j] = a2;
        // P <- M_t * P ; c <- M_t * c + b_t   (M_t = [[-a1,-a2],[1,0]])
        const float n00 = fmaf(-a1, p00, -a2 * p10);
        const float n01 = fmaf(-a1, p01, -a2 * p11);
        p10 = p00; p11 = p01; p00 = n00; p01 = n01;
        const float nc0 = fmaf(-a1, c0, fmaf(-a2, c1, xs[j]));
        c1 = c0; c0 = nc0;
    }

    // ---- truncated wave scan: d=1,2,4 full; d=8 c-only ----
#pragma unroll
    for (int d = 1; d <= 4; d <<= 1) {
        const float q00 = __shfl_up(p00, d, 64), q01 = __shfl_up(p01, d, 64);
        const float q10 = __shfl_up(p10, d, 64), q11 = __shfl_up(p11, d, 64);
        const float qc0 = __shfl_up(c0, d, 64),  qc1 = __shfl_up(c1, d, 64);
        if (lane >= d) {
            const float m00 = fmaf(p00, q00, p01 * q10);
            const float m01 = fmaf(p00, q01, p01 * q11);
            const float m10 = fmaf(p10, q00, p11 * q10);
            const float m11 = fmaf(p10, q01, p11 * q11);
            const float nc0 = fmaf(p00, qc0, fmaf(p01, qc1, c0));
            const float nc1 = fmaf(p10, qc0, fmaf(p11, qc1, c1));
            p00 = m00; p01 = m01; p10 = m10; p11 = m11; c0 = nc0; c1 = nc1;
        }
    }
    {   // d = 8: incoming P spans >=32 steps (norm <=1.5e-5) -> c only
        const float qc0 = __shfl_up(c0, 8, 64), qc1 = __shfl_up(c1, 8, 64);
        if (lane >= 8) {
            const float nc0 = fmaf(p00, qc0, fmaf(p01, qc1, c0));
            const float nc1 = fmaf(p10, qc0, fmaf(p11, qc1, c1));
            c0 = nc0; c1 = nc1;
        }
    }

    // ---- exclusive prefix; replay; store ----
    float y1 = __shfl_up(c0, 1, 64);
    float y2 = __shfl_up(c1, 1, 64);
    if (lane == 0) { y1 = 0.f; y2 = 0.f; }
    float ov[4];
#pragma unroll
    for (int j = 0; j < 4; ++j) {
        const float yt = fmaf(-a1s[j], y1, fmaf(-a2s[j], y2, xs[j]));
        y2 = y1; y1 = yt;
        ov[j] = yt;
    }
    if (lane >= WUP / 4 && t0 + 3 < T_LEN)
        *(float4*)(ob + t0) = make_float4(ov[0], ov[1], ov[2], ov[3]);
}

// ---------------- Fallback: fused R3 kernel (if ws too small) -----------
__global__ __launch_bounds__(256) void fused_kernel(
    const float* __restrict__ y, const float* __restrict__ A_exc,
    const float* __restrict__ A_loop, float* __restrict__ out) {
    const int tid  = threadIdx.x;
    const int widx = tid >> 6;
    const int lane = tid & 63;
    const int w = blockIdx.x * WPB + widx;
    const int b = w / NCH;
    const int c = w - b * NCH;
    const int s  = c * OUT_W;
    const int t0 = s - WUP + 4 * lane;

    const float* yb  = y      + (size_t)b * T_LEN;
    const float* aeb = A_exc  + (size_t)b * T_LEN * 6;
    const float* alb = A_loop + (size_t)b * T_LEN * 2;
    float*       ob  = out    + (size_t)b * T_LEN;

    const bool valid = (t0 >= 0) && (t0 + 3 < T_LEN);
    float4 yv, ae[6], al0, al1;
    if (valid) {
        yv = *(const float4*)(yb + t0);
        const float4* pa = (const float4*)(aeb + (size_t)t0 * 6);
#pragma unroll
        for (int i = 0; i < 6; ++i) ae[i] = pa[i];
        const float4* pl = (const float4*)(alb + (size_t)t0 * 2);
        al0 = pl[0]; al1 = pl[1];
    } else {
        yv = al0 = al1 = zero4();
#pragma unroll
        for (int i = 0; i < 6; ++i) ae[i] = zero4();
    }
    float4 hm1, hm2;
    hm1.x = __shfl_up(yv.x, 1, 64); hm1.y = __shfl_up(yv.y, 1, 64);
    hm1.z = __shfl_up(yv.z, 1, 64); hm1.w = __shfl_up(yv.w, 1, 64);
    hm2.x = __shfl_up(yv.x, 2, 64); hm2.y = __shfl_up(yv.y, 2, 64);
    hm2.z = __shfl_up(yv.z, 2, 64); hm2.w = __shfl_up(yv.w, 2, 64);
    if (lane == 0) hm1 = ld_g(yb, t0 - 4);
    if (lane <= 1) hm2 = ld_g(yb, t0 - 8);
    const float yw[12] = { hm2.x, hm2.y, hm2.z, hm2.w,
                           hm1.x, hm1.y, hm1.z, hm1.w,
                           yv.x, yv.y, yv.z, yv.w };
    const float* aef = (const float*)ae;
    const float alf[8] = { al0.x, al0.y, al0.z, al0.w,
                           al1.x, al1.y, al1.z, al1.w };
    float xs[4], a1s[4], a2s[4];
    float p00 = 1.f, p01 = 0.f, p10 = 0.f, p11 = 1.f, c0 = 0.f, c1 = 0.f;
#pragma unroll
    for (int j = 0; j < 4; ++j) {
        float xv = yw[8 + j];
#pragma unroll
        for (int k = 1; k <= 6; ++k)
            xv = fmaf(aef[j * 6 + (k - 1)], yw[8 + j - k], xv);
        xs[j] = xv;
        const float a1 = alf[2 * j], a2 = alf[2 * j + 1];
        a1s[j] = a1; a2s[j] = a2;
        const float n00 = fmaf(-a1, p00, -a2 * p10);
        const float n01 = fmaf(-a1, p01, -a2 * p11);
        p10 = p00; p11 = p01; p00 = n00; p01 = n01;
        const float nc0 = fmaf(-a1, c0, fmaf(-a2, c1, xv));
        c1 = c0; c0 = nc0;
    }
#pragma unroll
    for (int d = 1; d <= 4; d <<= 1) {
        const float q00 = __shfl_up(p00, d, 64), q01 = __shfl_up(p01, d, 64);
        const float q10 = __shfl_up(p10, d, 64), q11 = __shfl_up(p11, d, 64);
        const float qc0 = __shfl_up(c0, d, 64),  qc1 = __shfl_up(c1, d, 64);
        if (lane >= d) {
            const float m00 = fmaf(p00, q00, p01 * q10);
            const float m01 = fmaf(p00, q01, p01 * q11);
            const float m10 = fmaf(p10, q00, p11 * q10);
            const float m11 = fmaf(p10, q01, p11 * q11);
            const float nc0 = fmaf(p00, qc0, fmaf(p01, qc1, c0));
            const float nc1 = fmaf(p10, qc0, fmaf(p11, qc1, c1));
            p00 = m00; p01 = m01; p10 = m10; p11 = m11; c0 = nc0; c1 = nc1;
        }
    }
    {
        const float qc0 = __shfl_up(c0, 8, 64), qc1 = __shfl_up(c1, 8, 64);
        if (lane >= 8) {
            const float nc0 = fmaf(p00, qc0, fmaf(p01, qc1, c0));
            const float nc1 = fmaf(p10, qc0, fmaf(p11, qc1, c1));
            c0 = nc0; c1 = nc1;
        }
    }
    float y1 = __shfl_up(c0, 1, 64);
    float y2 = __shfl_up(c1, 1, 64);
    if (lane == 0) { y1 = 0.f; y2 = 0.f; }
    float ov[4];
#pragma unroll
    for (int j = 0; j < 4; ++j) {
        const float yt = fmaf(-a1s[j], y1, fmaf(-a2s[j], y2, xs[j]));
        y2 = y1; y1 = yt;
        ov[j] = yt;
    }
    if (lane >= WUP / 4 && t0 + 3 < T_LEN)
        *(float4*)(ob + t0) = make_float4(ov[0], ov[1], ov[2], ov[3]);
}

extern "C" void kernel_launch(void* const* d_in, const int* in_sizes, int n_in,
                              void* d_out, int out_size, void* d_ws, size_t ws_size,
                              hipStream_t stream) {
    const float* y      = (const float*)d_in[0];
    const float* A_exc  = (const float*)d_in[1];
    const float* A_loop = (const float*)d_in[2];
    float* out = (float*)d_out;

    const size_t x_bytes = (size_t)B_N * T_LEN * sizeof(float); // 16.94 MB
    if (ws_size >= x_bytes) {
        float* x = (float*)d_ws;
        const int wavesA = B_N * WPR;            // 16560
        fir_kernel<<<wavesA / 4, 256, 0, stream>>>(y, A_exc, x);
        const int wavesB = B_N * NCH;            // 18912
        iir_kernel<<<wavesB / WPB, 256, 0, stream>>>(x, A_loop, out);
    } else {
        const int waves = B_N * NCH;
        fused_kernel<<<waves / WPB, 256, 0, stream>>>(y, A_exc, A_loop, out);
    }
}